// Round 1
// baseline (138.892 us; speedup 1.0000x reference)
//
#include <hip/hip_runtime.h>

// Row-wise dot product: out[n] = sum_d x[n][d] * y[n][d]
// N = 16384 rows, D = 1024 cols, fp32 in / fp32 out.
// Memory-bound: 134 MB read @ ~6.3 TB/s -> ~21 us floor.
//
// One 256-thread block per row; each thread handles exactly one float4
// (256 * 4 = 1024 = D). Coalesced 16B/lane loads, wave shuffle reduce,
// cross-wave reduce via LDS, single store per block.

#define D 1024

__global__ __launch_bounds__(256) void rowdot_kernel(const float* __restrict__ x,
                                                     const float* __restrict__ y,
                                                     float* __restrict__ out) {
    const int row = blockIdx.x;
    const int t = threadIdx.x;

    const float4* xr = (const float4*)(x + (size_t)row * D);
    const float4* yr = (const float4*)(y + (size_t)row * D);

    float4 a = xr[t];
    float4 b = yr[t];

    float v = a.x * b.x + a.y * b.y + a.z * b.z + a.w * b.w;

    // wave-64 reduction
    #pragma unroll
    for (int off = 32; off > 0; off >>= 1) {
        v += __shfl_down(v, off, 64);
    }

    // cross-wave reduction (4 waves per block)
    __shared__ float partial[4];
    const int wave = t >> 6;
    const int lane = t & 63;
    if (lane == 0) partial[wave] = v;
    __syncthreads();
    if (t == 0) {
        out[row] = partial[0] + partial[1] + partial[2] + partial[3];
    }
}

extern "C" void kernel_launch(void* const* d_in, const int* in_sizes, int n_in,
                              void* d_out, int out_size, void* d_ws, size_t ws_size,
                              hipStream_t stream) {
    const float* x = (const float*)d_in[0];
    const float* y = (const float*)d_in[1];
    float* out = (float*)d_out;
    const int N = out_size;  // 16384 rows

    rowdot_kernel<<<N, 256, 0, stream>>>(x, y, out);
}